// Round 9
// baseline (181.571 us; speedup 1.0000x reference)
//
#include <hip/hip_runtime.h>
#include <stdint.h>

#define NROWS 8192
#define DDIM  128
#define NBLK  32                         // 32x32 grid of 256x256 tiles
#define LOG2E_X100 144.26950408889634f   // 100 / ln(2)
#define LN2F       0.6931471805599453f

typedef __bf16 bf16x8 __attribute__((ext_vector_type(8)));
typedef float  f32x4  __attribute__((ext_vector_type(4)));
typedef unsigned short u16x8 __attribute__((ext_vector_type(8)));

// Fragment-major (F) layout: for strip g (16 rows), k-chunk kc (32 cols):
//   1 KB block at byte offset (g*4+kc)*1024; lane L=(quad*16+c) piece at L*16,
//   holding row (g*16+c), bytes [(kc*4+quad)*16 .. +16).
// DMA (global->LDS), ds_read, and A-frag loads all run at linear lane*16.

__device__ __forceinline__ unsigned short f2bf_rne(float f) {
    union { float f; uint32_t u; } v; v.f = f;
    uint32_t r = (v.u + 0x7FFFu + ((v.u >> 16) & 1u)) >> 16;
    return (unsigned short)r;
}

__device__ __forceinline__ void async16(const unsigned short* g, unsigned char* l) {
    __builtin_amdgcn_global_load_lds(
        (const __attribute__((address_space(1))) unsigned int*)g,
        (__attribute__((address_space(3))) unsigned int*)l, 16, 0, 0);
}

// Kernel 1: fp32 -> bf16 into FRAGMENT-MAJOR layout. ts pre-scaled by
// 100*log2(e) (base-2 softmax space).
__global__ void convert_kernel(const float* __restrict__ ts, const float* __restrict__ nt,
                               unsigned short* __restrict__ ts_bf,
                               unsigned short* __restrict__ nt_bf,
                               float* __restrict__ acc, int* __restrict__ ticket) {
    const int nchunk = (NROWS * DDIM) / 8;
    int tid = blockIdx.x * blockDim.x + threadIdx.x;
    bool isNT = tid >= nchunk;
    int i = isNT ? (tid - nchunk) : tid;
    const float4* src = (const float4*)(isNT ? nt : ts) + i * 2;
    float4 v0 = src[0], v1 = src[1];
    float sc = isNT ? 1.0f : LOG2E_X100;
    u16x8 o;
    o[0] = f2bf_rne(v0.x * sc); o[1] = f2bf_rne(v0.y * sc);
    o[2] = f2bf_rne(v0.z * sc); o[3] = f2bf_rne(v0.w * sc);
    o[4] = f2bf_rne(v1.x * sc); o[5] = f2bf_rne(v1.y * sc);
    o[6] = f2bf_rne(v1.z * sc); o[7] = f2bf_rne(v1.w * sc);
    int row = i >> 4, chunk = i & 15;
    int g = row >> 4, c = row & 15;
    int kc = chunk >> 2, quad = chunk & 3;
    int off16 = (g * 4 + kc) * 64 + quad * 16 + c;
    ((u16x8*)(isNT ? nt_bf : ts_bf))[off16] = o;
    if (tid == 0) { *acc = 0.0f; *ticket = 0; }
}

// DMA one 64-row stage (16 KB contiguous in F layout), split across 8 waves.
__device__ __forceinline__ void dma_stage(const unsigned short* g, unsigned char* l,
                                          int lane, int wv) {
#pragma unroll
    for (int k = 0; k < 2; ++k) {
        int u = wv * 2 + k;
        async16(g + u * 512 + lane * 8, l + u * 1024);
    }
}

// Kernel 2: FUSED tile kernel. Block (I,J) computes the 256x256 tile of
// sim = ts . nt^T ONCE and extracts both row-stats (online, in-register)
// and col-stats (in-lane reduce -> cross-quad shuffle -> LDS -> 8-way combine).
// grid = (32, 32), 8 waves/block; wave owns 32 rows; 4 stages of 64 cols.
__global__ __launch_bounds__(512, 4) void tile_kernel(
        const unsigned short* __restrict__ ts_bf,
        const unsigned short* __restrict__ nt_bf,
        float* __restrict__ pm, float* __restrict__ ps, float* __restrict__ pd,
        float* __restrict__ cm, float* __restrict__ cs) {
    __shared__ unsigned char smem[2 * 16384];
    __shared__ float2 colp[8][256];            // per-wave col partials (m,s), 16 KB

    const int lane = threadIdx.x & 63;
    const int wv   = threadIdx.x >> 6;
    const int c    = lane & 15;
    const int quad = lane >> 4;
    const int I    = blockIdx.x;               // ts row-block
    const int J    = blockIdx.y;               // nt row-block (= col block of sim)
    const int rows0 = I * 256 + wv * 32;

    // A fragments: ts strips G0, G0+1 (lane-linear coalesced).
    const int G0 = I * 16 + wv * 2;
    bf16x8 a[2][4];
#pragma unroll
    for (int s = 0; s < 2; ++s)
#pragma unroll
        for (int kc = 0; kc < 4; ++kc)
            a[s][kc] = *(const bf16x8*)(ts_bf + ((G0 + s) * 4 + kc) * 512 + lane * 8);

    float m[2][4], ss[2][4], dg[2][4];
#pragma unroll
    for (int s = 0; s < 2; ++s)
#pragma unroll
        for (int r = 0; r < 4; ++r) { m[s][r] = -INFINITY; ss[s][r] = 0.0f; dg[s][r] = 0.0f; }

    // Diagonal: only block (I,I). Wave strips (local) 2wv,2wv+1 hit stage
    // t_d = wv>>1, slots l0 = (wv&1)*2 (+s).
    const bool diagB = (I == J);
    const int  t_d = wv >> 1;
    const int  l0  = (wv & 1) * 2;

    const unsigned short* bwalk = nt_bf + J * 16 * 2048;   // strip J*16

    dma_stage(bwalk, smem, lane, wv);
    __syncthreads();

    for (int t = 0; t < 4; ++t) {
        if (t + 1 < 4)
            dma_stage(bwalk + (t + 1) * 8192, smem + ((t + 1) & 1) * 16384, lane, wv);

        const unsigned char* buf = smem + (t & 1) * 16384 + lane * 16;

        f32x4 av[4][2];
#pragma unroll
        for (int l = 0; l < 4; ++l)
#pragma unroll
            for (int s = 0; s < 2; ++s) av[l][s] = (f32x4){0.f, 0.f, 0.f, 0.f};

#pragma unroll
        for (int kc = 0; kc < 4; ++kc) {
            bf16x8 b0 = *(const bf16x8*)(buf + kc * 1024);
            bf16x8 b1 = *(const bf16x8*)(buf + kc * 1024 + 4096);
            bf16x8 b2 = *(const bf16x8*)(buf + kc * 1024 + 8192);
            bf16x8 b3 = *(const bf16x8*)(buf + kc * 1024 + 12288);
            av[0][0] = __builtin_amdgcn_mfma_f32_16x16x32_bf16(a[0][kc], b0, av[0][0], 0, 0, 0);
            av[0][1] = __builtin_amdgcn_mfma_f32_16x16x32_bf16(a[1][kc], b0, av[0][1], 0, 0, 0);
            av[1][0] = __builtin_amdgcn_mfma_f32_16x16x32_bf16(a[0][kc], b1, av[1][0], 0, 0, 0);
            av[1][1] = __builtin_amdgcn_mfma_f32_16x16x32_bf16(a[1][kc], b1, av[1][1], 0, 0, 0);
            av[2][0] = __builtin_amdgcn_mfma_f32_16x16x32_bf16(a[0][kc], b2, av[2][0], 0, 0, 0);
            av[2][1] = __builtin_amdgcn_mfma_f32_16x16x32_bf16(a[1][kc], b2, av[2][1], 0, 0, 0);
            av[3][0] = __builtin_amdgcn_mfma_f32_16x16x32_bf16(a[0][kc], b3, av[3][0], 0, 0, 0);
            av[3][1] = __builtin_amdgcn_mfma_f32_16x16x32_bf16(a[1][kc], b3, av[3][1], 0, 0, 0);
        }

        // Row phase: mask + online row update. Masked values written back into
        // av so the col phase sees the same masked tile.
        const bool pd_ = diagB && (t == t_d);   // wave-uniform
#pragma unroll
        for (int s = 0; s < 2; ++s) {
#pragma unroll
            for (int r = 0; r < 4; ++r) {
                float x0 = av[0][s][r], x1 = av[1][s][r];
                float x2 = av[2][s][r], x3 = av[3][s][r];
                if (pd_) {
                    const int dslot = l0 + s;       // wave-uniform 0..3
                    bool onDiag = (c == quad * 4 + r);
                    float xv = dslot == 0 ? x0 : dslot == 1 ? x1 : dslot == 2 ? x2 : x3;
                    if (onDiag) dg[s][r] += xv;
                    float rep = onDiag ? xv : -1.0e30f;
                    if (dslot == 0) x0 = rep; else if (dslot == 1) x1 = rep;
                    else if (dslot == 2) x2 = rep; else x3 = rep;
                    av[0][s][r] = x0; av[1][s][r] = x1;
                    av[2][s][r] = x2; av[3][s][r] = x3;
                }
                float mn = fmaxf(fmaxf(fmaxf(x0, x1), fmaxf(x2, x3)), m[s][r]);
                float e  = __builtin_amdgcn_exp2f(m[s][r] - mn);
                float es = (__builtin_amdgcn_exp2f(x0 - mn) + __builtin_amdgcn_exp2f(x1 - mn))
                         + (__builtin_amdgcn_exp2f(x2 - mn) + __builtin_amdgcn_exp2f(x3 - mn));
                ss[s][r] = fmaf(ss[s][r], e, es);
                m[s][r] = mn;
            }
        }

        // Col phase: per slot, reduce the wave's 32 rows for its 16 columns.
#pragma unroll
        for (int l = 0; l < 4; ++l) {
            float v0 = av[l][0][0], v1 = av[l][0][1], v2 = av[l][0][2], v3 = av[l][0][3];
            float w0 = av[l][1][0], w1 = av[l][1][1], w2 = av[l][1][2], w3 = av[l][1][3];
            float m8 = fmaxf(fmaxf(fmaxf(v0, v1), fmaxf(v2, v3)),
                             fmaxf(fmaxf(w0, w1), fmaxf(w2, w3)));
            float s8 = ((__builtin_amdgcn_exp2f(v0 - m8) + __builtin_amdgcn_exp2f(v1 - m8))
                      + (__builtin_amdgcn_exp2f(v2 - m8) + __builtin_amdgcn_exp2f(v3 - m8)))
                     + ((__builtin_amdgcn_exp2f(w0 - m8) + __builtin_amdgcn_exp2f(w1 - m8))
                      + (__builtin_amdgcn_exp2f(w2 - m8) + __builtin_amdgcn_exp2f(w3 - m8)));
            // cross-quad combine (lanes with same c, quad 0..3)
#pragma unroll
            for (int off = 16; off < 64; off <<= 1) {
                float m2 = __shfl_xor(m8, off, 64);
                float s2 = __shfl_xor(s8, off, 64);
                float mn = fmaxf(m8, m2);
                s8 = s8 * __builtin_amdgcn_exp2f(m8 - mn) + s2 * __builtin_amdgcn_exp2f(m2 - mn);
                m8 = mn;
            }
            if (quad == 0) colp[wv][t * 64 + l * 16 + c] = make_float2(m8, s8);
        }
        __syncthreads();
    }

    // Row epilogue: 16-lane combine per quad; write row partials (idx row*32+J).
#pragma unroll
    for (int s = 0; s < 2; ++s) {
#pragma unroll
        for (int r = 0; r < 4; ++r) {
            float mm = m[s][r];
#pragma unroll
            for (int off = 1; off < 16; off <<= 1)
                mm = fmaxf(mm, __shfl_xor(mm, off, 64));
            float sv = ss[s][r] * __builtin_amdgcn_exp2f(m[s][r] - mm);
            float dd = dg[s][r];
#pragma unroll
            for (int off = 1; off < 16; off <<= 1) {
                sv += __shfl_xor(sv, off, 64);
                dd += __shfl_xor(dd, off, 64);
            }
            if (c == 0) {
                int row = rows0 + s * 16 + quad * 4 + r;
                int idx = row * NBLK + J;
                pm[idx] = mm; ps[idx] = sv; pd[idx] = dd;
            }
        }
    }

    // Col epilogue: combine the 8 waves' partials for the block's 256 columns.
    __syncthreads();
    int j = threadIdx.x;
    if (j < 256) {
        float2 p = colp[0][j];
        float M = p.x, S = p.y;
#pragma unroll
        for (int w = 1; w < 8; ++w) {
            float2 q = colp[w][j];
            float mn = fmaxf(M, q.x);
            S = S * __builtin_amdgcn_exp2f(M - mn) + q.y * __builtin_amdgcn_exp2f(q.x - mn);
            M = mn;
        }
        int col = J * 256 + j;
        cm[col * NBLK + I] = M;
        cs[col * NBLK + I] = S;
    }
}

// Kernel 3: per index i, merge 32 row-partials and 32 col-partials; the diag
// value (pd, written by the diagonal block) serves both directions.
__global__ void merge_kernel(const float* __restrict__ pm, const float* __restrict__ ps,
                             const float* __restrict__ pd, const float* __restrict__ cm,
                             const float* __restrict__ cs, float* __restrict__ acc,
                             int* __restrict__ ticket, float* __restrict__ out) {
    int i = blockIdx.x * blockDim.x + threadIdx.x;  // 0 .. NROWS-1
    const float* pmr = pm + i * NBLK;
    const float* psr = ps + i * NBLK;
    const float* pdr = pd + i * NBLK;
    const float* cmr = cm + i * NBLK;
    const float* csr = cs + i * NBLK;
    float mt = -INFINITY, mc = -INFINITY;
#pragma unroll
    for (int p = 0; p < NBLK; ++p) { mt = fmaxf(mt, pmr[p]); mc = fmaxf(mc, cmr[p]); }
    float st = 0.0f, sc = 0.0f, dt = 0.0f;
#pragma unroll
    for (int p = 0; p < NBLK; ++p) {
        st += psr[p] * __builtin_amdgcn_exp2f(pmr[p] - mt);
        sc += csr[p] * __builtin_amdgcn_exp2f(cmr[p] - mc);
        dt += pdr[p];
    }
    // lsm_r[i,i] + lsm_c[i,i], base-2
    float v = 2.0f * dt - mt - __builtin_amdgcn_logf(st)
                      - mc - __builtin_amdgcn_logf(sc);
#pragma unroll
    for (int off = 32; off; off >>= 1) v += __shfl_down(v, off, 64);
    __shared__ float wsum[4];
    if ((threadIdx.x & 63) == 0) wsum[threadIdx.x >> 6] = v;
    __syncthreads();
    if (threadIdx.x == 0) {
        atomicAdd(acc, wsum[0] + wsum[1] + wsum[2] + wsum[3]);
        __threadfence();
        int old = atomicAdd(ticket, 1);
        if (old == (int)gridDim.x - 1) {
            __threadfence();
            float tot = atomicAdd(acc, 0.0f);
            float t = -(tot * LN2F) / (2.0f * NROWS);
            if (!isfinite(t)) t = 0.0f;
            out[0] = t;
        }
    }
}

extern "C" void kernel_launch(void* const* d_in, const int* in_sizes, int n_in,
                              void* d_out, int out_size, void* d_ws, size_t ws_size,
                              hipStream_t stream) {
    const float* ts = (const float*)d_in[0];
    const float* nt = (const float*)d_in[1];
    float* out = (float*)d_out;

    unsigned short* ts_bf = (unsigned short*)d_ws;                 // 2 MB (fragment-major)
    unsigned short* nt_bf = ts_bf + NROWS * DDIM;                  // 2 MB (fragment-major)
    float* pm = (float*)(nt_bf + NROWS * DDIM);                    // 1 MB
    float* ps = pm + NROWS * NBLK;                                 // 1 MB
    float* pd = ps + NROWS * NBLK;                                 // 1 MB
    float* cm = pd + NROWS * NBLK;                                 // 1 MB
    float* cs = cm + NROWS * NBLK;                                 // 1 MB
    float* acc = cs + NROWS * NBLK;                                // 4 B
    int* ticket = (int*)(acc + 1);                                 // 4 B

    convert_kernel<<<1024, 256, 0, stream>>>(ts, nt, ts_bf, nt_bf, acc, ticket);
    tile_kernel<<<dim3(NBLK, NBLK), 512, 0, stream>>>(ts_bf, nt_bf, pm, ps, pd, cm, cs);
    merge_kernel<<<NROWS / 256, 256, 0, stream>>>(pm, ps, pd, cm, cs, acc, ticket, out);
}

// Round 10
// 122.617 us; speedup vs baseline: 1.4808x; 1.4808x over previous
//
#include <hip/hip_runtime.h>
#include <stdint.h>

#define NROWS 8192
#define DDIM  128
#define NBI   64                         // row blocks (128 rows each)
#define NBJ   32                         // col blocks (256 cols each)
#define LOG2E_X100 144.26950408889634f   // 100 / ln(2)
#define LN2F       0.6931471805599453f

typedef __bf16 bf16x8 __attribute__((ext_vector_type(8)));
typedef float  f32x4  __attribute__((ext_vector_type(4)));
typedef unsigned short u16x8 __attribute__((ext_vector_type(8)));

// Fragment-major (F) layout: for strip g (16 rows), k-chunk kc (32 cols):
//   1 KB block at byte offset (g*4+kc)*1024; lane L=(quad*16+c) piece at L*16,
//   holding row (g*16+c), bytes [(kc*4+quad)*16 .. +16).
// DMA (global->LDS), ds_read, and A-frag loads all run at linear lane*16.

__device__ __forceinline__ unsigned short f2bf_rne(float f) {
    union { float f; uint32_t u; } v; v.f = f;
    uint32_t r = (v.u + 0x7FFFu + ((v.u >> 16) & 1u)) >> 16;
    return (unsigned short)r;
}

__device__ __forceinline__ void async16(const unsigned short* g, unsigned char* l) {
    __builtin_amdgcn_global_load_lds(
        (const __attribute__((address_space(1))) unsigned int*)g,
        (__attribute__((address_space(3))) unsigned int*)l, 16, 0, 0);
}

// Kernel 1: fp32 -> bf16 into FRAGMENT-MAJOR layout; ts pre-scaled by
// 100*log2(e) (base-2 softmax space).
__global__ void convert_kernel(const float* __restrict__ ts, const float* __restrict__ nt,
                               unsigned short* __restrict__ ts_bf,
                               unsigned short* __restrict__ nt_bf,
                               float* __restrict__ acc, int* __restrict__ ticket) {
    const int nchunk = (NROWS * DDIM) / 8;
    int tid = blockIdx.x * blockDim.x + threadIdx.x;
    bool isNT = tid >= nchunk;
    int i = isNT ? (tid - nchunk) : tid;
    const float4* src = (const float4*)(isNT ? nt : ts) + i * 2;
    float4 v0 = src[0], v1 = src[1];
    float sc = isNT ? 1.0f : LOG2E_X100;
    u16x8 o;
    o[0] = f2bf_rne(v0.x * sc); o[1] = f2bf_rne(v0.y * sc);
    o[2] = f2bf_rne(v0.z * sc); o[3] = f2bf_rne(v0.w * sc);
    o[4] = f2bf_rne(v1.x * sc); o[5] = f2bf_rne(v1.y * sc);
    o[6] = f2bf_rne(v1.z * sc); o[7] = f2bf_rne(v1.w * sc);
    int row = i >> 4, chunk = i & 15;
    int g = row >> 4, c = row & 15;
    int kc = chunk >> 2, quad = chunk & 3;
    int off16 = (g * 4 + kc) * 64 + quad * 16 + c;
    ((u16x8*)(isNT ? nt_bf : ts_bf))[off16] = o;
    if (tid == 0) { *acc = 0.0f; *ticket = 0; }
}

// DMA one 64-col stage (16 KB contiguous in F layout), split across 8 waves.
__device__ __forceinline__ void dma_stage(const unsigned short* g, unsigned char* l,
                                          int lane, int wv) {
#pragma unroll
    for (int k = 0; k < 2; ++k) {
        int u = wv * 2 + k;
        async16(g + u * 512 + lane * 8, l + u * 1024);
    }
}

// Kernel 2: FUSED tile kernel, slim registers. Block (I,J) computes the
// 128x256 tile once; extracts row-stats (online, in-register) and col-stats
// (butterfly-max -> common-max exps -> butterfly-add; no (m,s) merges in the
// hot loop). Wave = 1 strip (16 rows). grid = (NBI, NBJ), 8 waves/block.
__global__ __launch_bounds__(512, 4) void tile_kernel(
        const unsigned short* __restrict__ ts_bf,
        const unsigned short* __restrict__ nt_bf,
        float* __restrict__ pm, float* __restrict__ ps,
        float* __restrict__ cm, float* __restrict__ cs,
        float* __restrict__ diag) {
    __shared__ unsigned char smem[2 * 16384];
    __shared__ float2 colp[8][256];            // per-wave col partials (M,S)

    const int lane = threadIdx.x & 63;
    const int wv   = threadIdx.x >> 6;
    const int c    = lane & 15;
    const int quad = lane >> 4;
    const int I    = blockIdx.x;               // row block (128 rows)
    const int J    = blockIdx.y;               // col block (256 cols)
    const int g    = I * 8 + wv;               // this wave's strip
    const int rows0 = g * 16;

    // A fragments: one strip, lane-linear coalesced (16 VGPRs).
    bf16x8 a[4];
#pragma unroll
    for (int kc = 0; kc < 4; ++kc)
        a[kc] = *(const bf16x8*)(ts_bf + (g * 4 + kc) * 512 + lane * 8);

    float m[4], ss[4], dg[4];
#pragma unroll
    for (int r = 0; r < 4; ++r) { m[r] = -INFINITY; ss[r] = 0.0f; dg[r] = 0.0f; }

    // Diagonal: block (I, I>>1); wave's diag tile index in block = 8*(I&1)+wv
    // -> stage t_d = 2*(I&1) + (wv>>2), slot l_d = wv&3.
    const bool diagB = (J == (I >> 1));
    const int  t_d = 2 * (I & 1) + (wv >> 2);
    const int  l_d = wv & 3;

    const unsigned short* bwalk = nt_bf + J * 16 * 2048;   // strip 16J

    dma_stage(bwalk, smem, lane, wv);
    __syncthreads();

    for (int t = 0; t < 4; ++t) {
        if (t + 1 < 4)
            dma_stage(bwalk + (t + 1) * 8192, smem + ((t + 1) & 1) * 16384, lane, wv);

        const unsigned char* buf = smem + (t & 1) * 16384 + lane * 16;

        f32x4 av[4];
#pragma unroll
        for (int l = 0; l < 4; ++l) av[l] = (f32x4){0.f, 0.f, 0.f, 0.f};

#pragma unroll
        for (int kc = 0; kc < 4; ++kc) {
            bf16x8 b0 = *(const bf16x8*)(buf + kc * 1024);
            bf16x8 b1 = *(const bf16x8*)(buf + kc * 1024 + 4096);
            bf16x8 b2 = *(const bf16x8*)(buf + kc * 1024 + 8192);
            bf16x8 b3 = *(const bf16x8*)(buf + kc * 1024 + 12288);
            av[0] = __builtin_amdgcn_mfma_f32_16x16x32_bf16(a[kc], b0, av[0], 0, 0, 0);
            av[1] = __builtin_amdgcn_mfma_f32_16x16x32_bf16(a[kc], b1, av[1], 0, 0, 0);
            av[2] = __builtin_amdgcn_mfma_f32_16x16x32_bf16(a[kc], b2, av[2], 0, 0, 0);
            av[3] = __builtin_amdgcn_mfma_f32_16x16x32_bf16(a[kc], b3, av[3], 0, 0, 0);
        }

        const bool pd_ = diagB && (t == t_d);   // wave-uniform

        // Row phase (never writes av; diag handled on local temps).
#pragma unroll
        for (int r = 0; r < 4; ++r) {
            float x0 = av[0][r], x1 = av[1][r], x2 = av[2][r], x3 = av[3][r];
            if (pd_) {
                bool onDiag = (c == quad * 4 + r);
                float xv = l_d == 0 ? x0 : l_d == 1 ? x1 : l_d == 2 ? x2 : x3;
                if (onDiag) dg[r] += xv;
                float rep = onDiag ? xv : -1.0e30f;
                if (l_d == 0) x0 = rep; else if (l_d == 1) x1 = rep;
                else if (l_d == 2) x2 = rep; else x3 = rep;
            }
            float mn = fmaxf(fmaxf(fmaxf(x0, x1), fmaxf(x2, x3)), m[r]);
            float e  = __builtin_amdgcn_exp2f(m[r] - mn);
            float es = (__builtin_amdgcn_exp2f(x0 - mn) + __builtin_amdgcn_exp2f(x1 - mn))
                     + (__builtin_amdgcn_exp2f(x2 - mn) + __builtin_amdgcn_exp2f(x3 - mn));
            ss[r] = fmaf(ss[r], e, es);
            m[r] = mn;
        }

        // Col phase: per slot, reduce this wave's 16 rows for 16 columns.
        // Pass 1: butterfly max (all quads get column max M, no exps).
        // Pass 2: exps vs common M, butterfly add (no exps).
#pragma unroll
        for (int l = 0; l < 4; ++l) {
            float v0 = av[l][0], v1 = av[l][1], v2 = av[l][2], v3 = av[l][3];
            if (pd_ && l == l_d) {              // re-apply mask inline
                v0 = (c == quad * 4 + 0) ? v0 : -1.0e30f;
                v1 = (c == quad * 4 + 1) ? v1 : -1.0e30f;
                v2 = (c == quad * 4 + 2) ? v2 : -1.0e30f;
                v3 = (c == quad * 4 + 3) ? v3 : -1.0e30f;
            }
            float M = fmaxf(fmaxf(v0, v1), fmaxf(v2, v3));
            M = fmaxf(M, __shfl_xor(M, 16, 64));
            M = fmaxf(M, __shfl_xor(M, 32, 64));
            float S = (__builtin_amdgcn_exp2f(v0 - M) + __builtin_amdgcn_exp2f(v1 - M))
                    + (__builtin_amdgcn_exp2f(v2 - M) + __builtin_amdgcn_exp2f(v3 - M));
            S += __shfl_xor(S, 16, 64);
            S += __shfl_xor(S, 32, 64);
            if (quad == 0) colp[wv][t * 64 + l * 16 + c] = make_float2(M, S);
        }
        __syncthreads();
    }

    // Row epilogue: combine the 16 lanes of each quad; write row partials.
#pragma unroll
    for (int r = 0; r < 4; ++r) {
        float mm = m[r];
#pragma unroll
        for (int off = 1; off < 16; off <<= 1)
            mm = fmaxf(mm, __shfl_xor(mm, off, 64));
        float sv = ss[r] * __builtin_amdgcn_exp2f(m[r] - mm);
        float dd = dg[r];
#pragma unroll
        for (int off = 1; off < 16; off <<= 1) {
            sv += __shfl_xor(sv, off, 64);
            dd += __shfl_xor(dd, off, 64);
        }
        if (c == 0) {
            int row = rows0 + quad * 4 + r;
            pm[row * NBJ + J] = mm;
            ps[row * NBJ + J] = sv;
            if (diagB) diag[row] = dd;
        }
    }

    // Col epilogue: combine 8 waves' partials for this block's 256 columns.
    __syncthreads();
    int j = threadIdx.x;
    if (j < 256) {
        float2 p = colp[0][j];
        float M = p.x, S = p.y;
#pragma unroll
        for (int w = 1; w < 8; ++w) {
            float2 q = colp[w][j];
            float mn = fmaxf(M, q.x);
            S = S * __builtin_amdgcn_exp2f(M - mn) + q.y * __builtin_amdgcn_exp2f(q.x - mn);
            M = mn;
        }
        int col = J * 256 + j;
        cm[col * NBI + I] = M;
        cs[col * NBI + I] = S;
    }
}

// Kernel 3: per index i, merge 32 row-partials + 64 col-partials + diag;
// block-reduce, atomicAdd, last block finalizes (base-2 -> natural via ln2).
__global__ void merge_kernel(const float* __restrict__ pm, const float* __restrict__ ps,
                             const float* __restrict__ cm, const float* __restrict__ cs,
                             const float* __restrict__ diag, float* __restrict__ acc,
                             int* __restrict__ ticket, float* __restrict__ out) {
    int i = blockIdx.x * blockDim.x + threadIdx.x;  // 0 .. NROWS-1
    const float* pmr = pm + i * NBJ;
    const float* psr = ps + i * NBJ;
    const float* cmr = cm + i * NBI;
    const float* csr = cs + i * NBI;
    float mt = -INFINITY, mc = -INFINITY;
#pragma unroll
    for (int p = 0; p < NBJ; ++p) mt = fmaxf(mt, pmr[p]);
#pragma unroll
    for (int p = 0; p < NBI; ++p) mc = fmaxf(mc, cmr[p]);
    float st = 0.0f, sc = 0.0f;
#pragma unroll
    for (int p = 0; p < NBJ; ++p) st += psr[p] * __builtin_amdgcn_exp2f(pmr[p] - mt);
#pragma unroll
    for (int p = 0; p < NBI; ++p) sc += csr[p] * __builtin_amdgcn_exp2f(cmr[p] - mc);
    float d = diag[i];
    // lsm_r[i,i] + lsm_c[i,i], base-2
    float v = 2.0f * d - mt - __builtin_amdgcn_logf(st)
                      - mc - __builtin_amdgcn_logf(sc);
#pragma unroll
    for (int off = 32; off; off >>= 1) v += __shfl_down(v, off, 64);
    __shared__ float wsum[4];
    if ((threadIdx.x & 63) == 0) wsum[threadIdx.x >> 6] = v;
    __syncthreads();
    if (threadIdx.x == 0) {
        atomicAdd(acc, wsum[0] + wsum[1] + wsum[2] + wsum[3]);
        __threadfence();
        int old = atomicAdd(ticket, 1);
        if (old == (int)gridDim.x - 1) {
            __threadfence();
            float tot = atomicAdd(acc, 0.0f);
            float t = -(tot * LN2F) / (2.0f * NROWS);
            if (!isfinite(t)) t = 0.0f;
            out[0] = t;
        }
    }
}

extern "C" void kernel_launch(void* const* d_in, const int* in_sizes, int n_in,
                              void* d_out, int out_size, void* d_ws, size_t ws_size,
                              hipStream_t stream) {
    const float* ts = (const float*)d_in[0];
    const float* nt = (const float*)d_in[1];
    float* out = (float*)d_out;

    unsigned short* ts_bf = (unsigned short*)d_ws;                 // 2 MB (fragment-major)
    unsigned short* nt_bf = ts_bf + NROWS * DDIM;                  // 2 MB (fragment-major)
    float* pm = (float*)(nt_bf + NROWS * DDIM);                    // 1 MB
    float* ps = pm + NROWS * NBJ;                                  // 1 MB
    float* cm = ps + NROWS * NBJ;                                  // 2 MB
    float* cs = cm + NROWS * NBI;                                  // 2 MB
    float* diag = cs + NROWS * NBI;                                // 32 KB
    float* acc = diag + NROWS;                                     // 4 B
    int* ticket = (int*)(acc + 1);                                 // 4 B

    convert_kernel<<<1024, 256, 0, stream>>>(ts, nt, ts_bf, nt_bf, acc, ticket);
    tile_kernel<<<dim3(NBI, NBJ), 512, 0, stream>>>(ts_bf, nt_bf, pm, ps, cm, cs, diag);
    merge_kernel<<<NROWS / 256, 256, 0, stream>>>(pm, ps, cm, cs, diag, acc, ticket, out);
}